// Round 4
// baseline (1133.026 us; speedup 1.0000x reference)
//
#include <hip/hip_runtime.h>
#include <hip/hip_bf16.h>
#include <math.h>

// Transformer block for MI355X (gfx950). Inputs/outputs are FLOAT32 (per the
// reference contract); compute is bf16-MFMA internally.
// GEMMs: m97 structure (128x128 tile, BK=32, global_load_lds width 16).
// Attention: per-wave flash (16 q-rows/wave), MFMA QK^T and PV, LDS P-transpose.
// Weights converted f32->bf16 just-in-time into one rotating workspace slot.
// R3: workspace layout hardened — peak 89.7MB, no slot overrun (w1x overlays
// dead xn+q+k span; xn2 lives in dead v slot).

typedef __bf16 bf16x8 __attribute__((ext_vector_type(8)));
typedef float f32x4 __attribute__((ext_vector_type(4)));

#define MFMA16(a, b, c) __builtin_amdgcn_mfma_f32_16x16x32_bf16(a, b, c, 0, 0, 0)

__device__ __forceinline__ void async_cp16(const void* g, void* l) {
  __builtin_amdgcn_global_load_lds((__attribute__((address_space(1))) void*)g,
                                   (__attribute__((address_space(3))) void*)l,
                                   16, 0, 0);
}

// --------------------------------------------------------------- f32 -> bf16
__global__ __launch_bounds__(256) void cvt_k(const float* __restrict__ s,
                                             __bf16* __restrict__ d, long n) {
  const long i = ((long)blockIdx.x * 256 + threadIdx.x) * 8;
  if (i >= n) return;
  f32x4 a = *(const f32x4*)(s + i);
  f32x4 b = *(const f32x4*)(s + i + 4);
  bf16x8 o;
#pragma unroll
  for (int j = 0; j < 4; ++j) {
    o[j] = (__bf16)a[j];
    o[4 + j] = (__bf16)b[j];
  }
  *(bf16x8*)(d + i) = o;
}

// ---------------------------------------------------------------- GEMM (B^T)
// C[M,N] = A[M,K] * B[N,K]^T   (A,B bf16; C dtype CT)
// EPI=0: store. EPI=1: += R (residual). EPI=2: *= silu(R) (R=w1x, in-place h).
template <int EPI, typename CT, typename RT>
__global__ __launch_bounds__(256) void gemm_bt(
    const __bf16* __restrict__ A, const __bf16* __restrict__ B,
    CT* C, const RT* R, int M, int N, int K) {
  __shared__ __attribute__((aligned(16))) __bf16 sA[128 * 32];
  __shared__ __attribute__((aligned(16))) __bf16 sB[128 * 32];
  const int tid = threadIdx.x;
  const int lane = tid & 63;
  const int wave = tid >> 6;
  const int wm = (wave >> 1) << 6;   // wave's 64x64 quadrant
  const int wn = (wave & 1) << 6;
  const int ln15 = lane & 15;
  const int kq8 = (lane >> 4) << 3;  // quad*8
  const long blockM = (long)blockIdx.y << 7;
  const long blockN = (long)blockIdx.x << 7;

  // staging: thread t covers row t/4 (and +64), k-cols (t%4)*8..+8; LDS dest is
  // linear in lane (base + lane*16B) per the global_load_lds G5 caveat.
  const int srow = tid >> 2;
  const int scol = (tid & 3) << 3;
  const __bf16* gA = A + (blockM + srow) * (long)K + scol;
  const __bf16* gB = B + (blockN + srow) * (long)K + scol;
  __bf16* lA = sA + tid * 8;
  __bf16* lB = sB + tid * 8;

  f32x4 acc[4][4] = {};
  const int KT = K >> 5;

  async_cp16(gA, lA);
  async_cp16(gA + 64 * (long)K, lA + 2048);
  async_cp16(gB, lB);
  async_cp16(gB + 64 * (long)K, lB + 2048);

  for (int kt = 0; kt < KT; ++kt) {
    __builtin_amdgcn_s_waitcnt(0);  // drain this wave's global_load_lds
    __syncthreads();                // all waves' staging visible
    bf16x8 af[4], bfr[4];
#pragma unroll
    for (int i = 0; i < 4; ++i)
      af[i] = *(const bf16x8*)&sA[(wm + i * 16 + ln15) * 32 + kq8];
#pragma unroll
    for (int j = 0; j < 4; ++j)
      bfr[j] = *(const bf16x8*)&sB[(wn + j * 16 + ln15) * 32 + kq8];
    __syncthreads();                // frag reads done before re-staging
    if (kt + 1 < KT) {
      const __bf16* a2 = gA + (long)(kt + 1) * 32;
      const __bf16* b2 = gB + (long)(kt + 1) * 32;
      async_cp16(a2, lA);
      async_cp16(a2 + 64 * (long)K, lA + 2048);
      async_cp16(b2, lB);
      async_cp16(b2 + 64 * (long)K, lB + 2048);
    }
#pragma unroll
    for (int i = 0; i < 4; ++i)
#pragma unroll
      for (int j = 0; j < 4; ++j)
        acc[i][j] = MFMA16(af[i], bfr[j], acc[i][j]);
  }

  // C/D layout (m89): col = lane&15, row = quad*4 + reg
  const int rq4 = (lane >> 4) << 2;
#pragma unroll
  for (int i = 0; i < 4; ++i)
#pragma unroll
    for (int j = 0; j < 4; ++j)
#pragma unroll
      for (int r = 0; r < 4; ++r) {
        const long grow = blockM + wm + i * 16 + rq4 + r;
        const long gcol = blockN + wn + j * 16 + ln15;
        const long idx = grow * N + gcol;
        float v = acc[i][j][r];
        if (EPI == 1) v += (float)R[idx];
        if (EPI == 2) {
          const float w = (float)R[idx];
          v *= w / (1.f + __expf(-w));  // silu(w1x) * (xn2.W3^T)
        }
        C[idx] = (CT)v;
      }
}

// ------------------------------------------------------------ flash attention
// one wave per (b, h, 16 q-rows); key tiles of 32; causal; finite sentinels.
__global__ __launch_bounds__(64) void attn_k(
    const __bf16* __restrict__ q, const __bf16* __restrict__ k,
    const __bf16* __restrict__ v, __bf16* __restrict__ o) {
  __shared__ __attribute__((aligned(16))) __bf16 sP[16 * 32];
  const int lane = threadIdx.x;
  const int ln15 = lane & 15;
  const int quad = lane >> 4;
  const int qt = blockIdx.x;
  const int h = blockIdx.y;
  const int b = blockIdx.z;
  const int S = 2048;
  const int qb = qt << 4;
  const long bh = (long)b * S * 2048 + h * 128;
  const float NEG = -1.0e4f;  // finite; |true score| < ~1e2

  bf16x8 qf[4];  // A-frag (m120): Q[m=ln15][d = kb*32 + quad*8 + j]
  const __bf16* qp = q + bh + (long)(qb + ln15) * 2048 + quad * 8;
#pragma unroll
  for (int kb = 0; kb < 4; ++kb) qf[kb] = *(const bf16x8*)(qp + kb * 32);

  f32x4 oacc[8] = {};
  float mrow[4] = {NEG, NEG, NEG, NEG};
  float lrow[4] = {};
  const float scale = 0.08838834764831845f;  // 1/sqrt(128)

  const int nkt = (qt + 2) >> 1;
  for (int kt = 0; kt < nkt; ++kt) {
    const int kbase = kt << 5;
    f32x4 s[2] = {};
#pragma unroll
    for (int c = 0; c < 2; ++c) {
      const __bf16* kp = k + bh + (long)(kbase + c * 16 + ln15) * 2048 + quad * 8;
#pragma unroll
      for (int kb = 0; kb < 4; ++kb) {
        bf16x8 kf = *(const bf16x8*)(kp + kb * 32);
        s[c] = MFMA16(qf[kb], kf, s[c]);
      }
    }
#pragma unroll
    for (int r = 0; r < 4; ++r) {
      const int qrow = qb + quad * 4 + r;
      const bool m0 = (kbase + ln15 > qrow);
      const bool m1 = (kbase + 16 + ln15 > qrow);
      const float s0 = m0 ? NEG : s[0][r] * scale;
      const float s1 = m1 ? NEG : s[1][r] * scale;
      float tm = fmaxf(s0, s1);
#pragma unroll
      for (int off = 1; off < 16; off <<= 1) tm = fmaxf(tm, __shfl_xor(tm, off));
      const float mnew = fmaxf(mrow[r], tm);
      const float alpha = __expf(mrow[r] - mnew);  // arg <= 0: no inf
      mrow[r] = mnew;
      const float p0 = m0 ? 0.f : __expf(s0 - mnew);
      const float p1 = m1 ? 0.f : __expf(s1 - mnew);
      float rs = p0 + p1;
#pragma unroll
      for (int off = 1; off < 16; off <<= 1) rs += __shfl_xor(rs, off);
      lrow[r] = lrow[r] * alpha + rs;
#pragma unroll
      for (int nt = 0; nt < 8; ++nt) oacc[nt][r] *= alpha;
      sP[(quad * 4 + r) * 32 + ln15] = (__bf16)p0;
      sP[(quad * 4 + r) * 32 + 16 + ln15] = (__bf16)p1;
    }
    __syncthreads();  // P writes -> visible for transposed read
    bf16x8 pa = *(const bf16x8*)&sP[ln15 * 32 + quad * 8];  // A-layout P
    __syncthreads();  // read retired before next iter's writes
    const __bf16* vbase = v + bh + (long)kbase * 2048;
#pragma unroll
    for (int nt = 0; nt < 8; ++nt) {
      bf16x8 vf;  // B-frag: V[key = quad*8 + j][dim = nt*16 + ln15]
      const __bf16* vp = vbase + (long)(quad * 8) * 2048 + nt * 16 + ln15;
#pragma unroll
      for (int j = 0; j < 8; ++j) vf[j] = vp[(long)j * 2048];
      oacc[nt] = MFMA16(pa, vf, oacc[nt]);
    }
  }

  __bf16* op = o + bh + (long)qb * 2048;
#pragma unroll
  for (int nt = 0; nt < 8; ++nt)
#pragma unroll
    for (int r = 0; r < 4; ++r)
      op[(long)(quad * 4 + r) * 2048 + nt * 16 + ln15] =
          (__bf16)(oacc[nt][r] / lrow[r]);
}

// ------------------------------------------------------ RMSNorm (f32 -> bf16)
__global__ __launch_bounds__(256) void rmsnorm_k(
    const float* __restrict__ x, const float* __restrict__ g,
    __bf16* __restrict__ out) {
  __shared__ float red[4];
  const int row = blockIdx.x;
  const int tid = threadIdx.x;
  f32x4 xa = *(const f32x4*)(x + (long)row * 2048 + tid * 8);
  f32x4 xb = *(const f32x4*)(x + (long)row * 2048 + tid * 8 + 4);
  float xf[8];
  float ss = 0.f;
#pragma unroll
  for (int j = 0; j < 4; ++j) {
    xf[j] = xa[j];
    xf[4 + j] = xb[j];
  }
#pragma unroll
  for (int j = 0; j < 8; ++j) ss += xf[j] * xf[j];
#pragma unroll
  for (int off = 32; off > 0; off >>= 1) ss += __shfl_xor(ss, off);
  if ((tid & 63) == 0) red[tid >> 6] = ss;
  __syncthreads();
  const float inv = rsqrtf((red[0] + red[1] + red[2] + red[3]) * (1.f / 2048.f) + 1e-5f);
  f32x4 ga = *(const f32x4*)(g + tid * 8);
  f32x4 gb = *(const f32x4*)(g + tid * 8 + 4);
  bf16x8 ov;
#pragma unroll
  for (int j = 0; j < 4; ++j) {
    ov[j] = (__bf16)(xf[j] * inv * ga[j]);
    ov[4 + j] = (__bf16)(xf[4 + j] * inv * gb[j]);
  }
  *(bf16x8*)(out + (long)row * 2048 + tid * 8) = ov;
}

// ----------------------------------------------------------------- RoPE (bf16)
__global__ __launch_bounds__(256) void rope_k(__bf16* __restrict__ t) {
  const long idx = (long)blockIdx.x * 256 + threadIdx.x;  // (row, h, kpair)
  const int kp = idx & 63;
  const int h = (idx >> 6) & 15;
  const long row = idx >> 10;
  const int pos = (int)(row & 2047);
  const float freq = exp2f((float)kp * (-13.287712379549449f / 64.0f));
  float sn, cs;
  sincosf((float)pos * freq, &sn, &cs);
  __bf16* p = t + row * 2048 + h * 128 + kp * 2;
  const float e = (float)p[0], od = (float)p[1];
  p[0] = (__bf16)(e * cs - od * sn);
  p[1] = (__bf16)(e * sn + od * cs);
}

// -------------------------------------------------------------------- launcher
extern "C" void kernel_launch(void* const* d_in, const int* in_sizes, int n_in,
                              void* d_out, int out_size, void* d_ws, size_t ws_size,
                              hipStream_t stream) {
  const float* x = (const float*)d_in[0];
  const float* Wq = (const float*)d_in[1];
  const float* Wk = (const float*)d_in[2];
  const float* Wv = (const float*)d_in[3];
  const float* Wo = (const float*)d_in[4];
  const float* W1 = (const float*)d_in[5];
  const float* W2 = (const float*)d_in[6];
  const float* W3 = (const float*)d_in[7];
  const float* g1 = (const float*)d_in[8];
  const float* g2 = (const float*)d_in[9];
  float* out = (float*)d_out;
  char* ws = (char*)d_ws;

  const long NDD = 2048L * 2048;   // 4,194,304
  const long NFD = 5504L * 2048;   // 11,272,192
  const long WSLOT = 22544384;     // NFD * 2 bytes (max weight, bf16)
  const long MB16 = 16777216;      // 4096*2048*2 bytes (bf16 activation)

  __bf16* wslot = (__bf16*)(ws);                  // rotating bf16 weight
  __bf16* xn = (__bf16*)(ws + WSLOT);             // rmsnorm1 out / attn out
  __bf16* qb = (__bf16*)(ws + WSLOT + MB16);      // q
  __bf16* kb = (__bf16*)(ws + WSLOT + 2 * MB16);  // k
  __bf16* vb = (__bf16*)(ws + WSLOT + 3 * MB16);  // v
  __bf16* attn = xn;
  __bf16* xn2 = vb;        // v dead after attn; rmsnorm2 out lives here
  __bf16* w1x = xn;        // 43MB over dead xn+q+k span [WSLOT, WSLOT+45.1MB);
                           // ends 67.6MB < xn2 offset 72.9MB -- disjoint.
  // peak ws: WSLOT + 4*MB16 = 89.7MB

  rmsnorm_k<<<4096, 256, 0, stream>>>(x, g1, xn);

  cvt_k<<<2048, 256, 0, stream>>>(Wq, wslot, NDD);
  gemm_bt<0, __bf16, float><<<dim3(16, 32), 256, 0, stream>>>(
      xn, wslot, qb, nullptr, 4096, 2048, 2048);
  cvt_k<<<2048, 256, 0, stream>>>(Wk, wslot, NDD);
  gemm_bt<0, __bf16, float><<<dim3(16, 32), 256, 0, stream>>>(
      xn, wslot, kb, nullptr, 4096, 2048, 2048);
  cvt_k<<<2048, 256, 0, stream>>>(Wv, wslot, NDD);
  gemm_bt<0, __bf16, float><<<dim3(16, 32), 256, 0, stream>>>(
      xn, wslot, vb, nullptr, 4096, 2048, 2048);

  rope_k<<<16384, 256, 0, stream>>>(qb);
  rope_k<<<16384, 256, 0, stream>>>(kb);
  attn_k<<<dim3(128, 16, 2), 64, 0, stream>>>(qb, kb, vb, attn);

  cvt_k<<<2048, 256, 0, stream>>>(Wo, wslot, NDD);
  gemm_bt<1, float, float><<<dim3(16, 32), 256, 0, stream>>>(
      attn, wslot, out, x, 4096, 2048, 2048);  // out = attn.Wo^T + x (f32)

  rmsnorm_k<<<4096, 256, 0, stream>>>(out, g2, xn2);

  cvt_k<<<5504, 256, 0, stream>>>(W1, wslot, NFD);
  gemm_bt<0, __bf16, float><<<dim3(43, 32), 256, 0, stream>>>(
      xn2, wslot, w1x, nullptr, 4096, 5504, 2048);
  cvt_k<<<5504, 256, 0, stream>>>(W3, wslot, NFD);
  gemm_bt<2, __bf16, __bf16><<<dim3(43, 32), 256, 0, stream>>>(
      xn2, wslot, w1x, w1x, 4096, 5504, 2048);  // h = silu(w1x)*w3x in-place
  cvt_k<<<5504, 256, 0, stream>>>(W2, wslot, NFD);
  gemm_bt<1, float, float><<<dim3(16, 32), 256, 0, stream>>>(
      w1x, wslot, out, out, 4096, 2048, 5504);  // out += h.W2^T (f32)
}